// Round 10
// baseline (222.720 us; speedup 1.0000x reference)
//
#include <hip/hip_runtime.h>

#define HW    16384
#define WDIM  128
#define CDIM  64
#define NBG   1024   // (b, rowgroup of 4): 32 images x 32 groups
#define NBC   2048

// ws layout (bytes), all zeroed at launch:
//   [0)       double acc[6][2048]   sf,s0,sj,sqj,si,sqi per (b,c)
//   [98304)   u64 apack[2048]       packed (ordered-max:32 | 16383-flatidx)
//   [114688)  double ga[2]          a1,a2 global
#define WS_ZERO_BYTES (6*2048*8 + 2048*8 + 16)

__device__ __forceinline__ unsigned ordf(float x) {
    unsigned u = __float_as_uint(x);
    return u ^ ((u >> 31) ? 0xFFFFFFFFu : 0x80000000u);
}

// Single pass. Block = (b, 4-row group). Tile [64c][128px] in LDS, stride 129
// (EVERY phase conflict-free: 2a col reads consecutive, 2b rows (ch+i)%32,
// staging 2-4 way). Next row's 8 float4 prefetched in regs, pinned by
// sched_barrier; barriers are lgkm-only so the prefetch stays in flight.
// Per-row results go straight to global double-atomics (no partial arrays).
__global__ __launch_bounds__(256, 4) void f_fused(const float* __restrict__ feat,
                                                  double* __restrict__ acc,
                                                  unsigned long long* __restrict__ apack,
                                                  double* __restrict__ ga) {
    __shared__ float tile[CDIM * 129];    // 33024 B
    __shared__ float scratch[1536];       // union: sc2[384] / scb[4*64*6]

    const int t = threadIdx.x;
    const int bq = blockIdx.x;            // b*32 + rowgroup
    const int b = bq >> 5, rg = bq & 31;
    const int row0 = rg * 4;
    const float* srcb = feat + (size_t)b * (CDIM * HW) + (size_t)row0 * WDIM;

    const int px = t & 127, half = t >> 7;               // 2a roles
    const int ch = t & 63, sub = t >> 6, p0 = sub * 32;  // 2b roles

    // prologue: row 0 loads
    float4 nbuf[8];
    #pragma unroll
    for (int k = 0; k < 8; ++k) {
        int idx = k * 256 + t;
        nbuf[k] = *(const float4*)(srcb + (size_t)(idx >> 5) * HW + (idx & 31) * 4);
    }

    #pragma unroll
    for (int r = 0; r < 4; ++r) {
        const int row = row0 + r;

        // ---- stage current row (waitcnt on nbuf auto-inserted here)
        #pragma unroll
        for (int k = 0; k < 8; ++k) {
            int idx = k * 256 + t;
            int c = idx >> 5, g = idx & 31;
            float* dst = &tile[c * 129 + g * 4];
            dst[0] = nbuf[k].x; dst[1] = nbuf[k].y; dst[2] = nbuf[k].z; dst[3] = nbuf[k].w;
        }
        // ---- issue NEXT row's loads; sched_barrier pins them (cannot sink)
        if (r < 3) {
            #pragma unroll
            for (int k = 0; k < 8; ++k) {
                int idx = k * 256 + t;
                nbuf[k] = *(const float4*)(srcb + (size_t)(r + 1) * WDIM
                                           + (size_t)(idx >> 5) * HW + (idx & 31) * 4);
            }
        }
        __builtin_amdgcn_sched_barrier(0);
        // B1: tile ready — lgkm only, prefetch stays in flight
        asm volatile("s_waitcnt lgkmcnt(0)" ::: "memory");
        __builtin_amdgcn_s_barrier();

        // ---- 2a: pixel-direction top2 + S2 (px fixed, scan 32 channels)
        float m1 = -INFINITY, m2 = -INFINITY, s2 = 0.f;
        #pragma unroll
        for (int cc = 0; cc < 32; ++cc) {
            float x = tile[(half * 32 + cc) * 129 + px];
            m2 = __builtin_amdgcn_fmed3f(x, m1, m2);   // new 2nd-max (old m1 >= m2)
            m1 = fmaxf(m1, x);
            s2 = fmaf(x, x, s2);
        }
        if (half) { scratch[px * 3] = m1; scratch[px * 3 + 1] = m2; scratch[px * 3 + 2] = s2; }
        asm volatile("s_waitcnt lgkmcnt(0)" ::: "memory");  // B2
        __builtin_amdgcn_s_barrier();

        // ---- 2b: channel-direction scan (ch fixed, 32 px serial)
        float bm = -INFINITY; int bi = 0;
        float sf = 0.f, s0 = 0.f, sjl = 0.f, sql = 0.f;
        #pragma unroll
        for (int i = 0; i < 32; ++i) {
            float x = tile[ch * 129 + p0 + i];
            if (x > bm) { bm = x; bi = i; }     // ascending i: first occurrence
            sf += x;
            float q = x * x;
            s0 += q;
            sjl = fmaf(q, (float)i, sjl);
            sql = fmaf(q, (float)(i * i), sql);
        }

        // ---- 2a merge + per-pixel closed form + wave reduce -> global atomics
        if (!half) {
            float n1 = scratch[px * 3], n2 = scratch[px * 3 + 1], s2b = scratch[px * 3 + 2];
            float mm1 = fmaxf(m1, n1);
            float mm2 = fmaxf(fminf(m1, n1), fmaxf(m2, n2));
            float S2 = s2 + s2b;
            float qq = mm1 * mm1, rr = S2 - qq;
            float a1 = qq * rr + mm2 * mm2 * qq;
            float a2 = mm1 * rr + mm2 * qq;
            #pragma unroll
            for (int off = 32; off > 0; off >>= 1) {
                a1 += __shfl_down(a1, off);
                a2 += __shfl_down(a2, off);
            }
            if ((t & 63) == 0) {
                atomicAdd(&ga[0], (double)a1);
                atomicAdd(&ga[1], (double)a2);
            }
        }
        asm volatile("s_waitcnt lgkmcnt(0)" ::: "memory");  // B3: sc2 consumed
        __builtin_amdgcn_s_barrier();

        // ---- write 2b sub-partials (scb region)
        {
            float sj  = fmaf((float)p0, s0, sjl);
            float sqj = fmaf((float)(p0 * p0), s0, fmaf(2.f * (float)p0, sjl, sql));
            int o = (sub * 64 + ch) * 6;
            scratch[o]     = bm;
            scratch[o + 1] = __int_as_float(p0 + bi);
            scratch[o + 2] = sf; scratch[o + 3] = s0;
            scratch[o + 4] = sj; scratch[o + 5] = sqj;
        }
        asm volatile("s_waitcnt lgkmcnt(0)" ::: "memory");  // B4
        __builtin_amdgcn_s_barrier();

        // ---- combine 4 subs per channel -> global double atomics
        if (t < 64) {
            float M = -INFINITY; int P = 0;
            float SF = 0.f, S0 = 0.f, SJ = 0.f, SQ = 0.f;
            #pragma unroll
            for (int s = 0; s < 4; ++s) {       // ascending sub = ascending px
                int oo = (s * 64 + t) * 6;
                float m = scratch[oo];
                if (m > M) { M = m; P = __float_as_int(scratch[oo + 1]); }
                SF += scratch[oo + 2]; S0 += scratch[oo + 3];
                SJ += scratch[oo + 4]; SQ += scratch[oo + 5];
            }
            const int bc = b * 64 + t;
            const double dS0 = (double)S0, drow = (double)row;
            atomicAdd(&acc[          bc], (double)SF);
            atomicAdd(&acc[2048    + bc], dS0);
            atomicAdd(&acc[2*2048  + bc], (double)SJ);
            atomicAdd(&acc[3*2048  + bc], (double)SQ);
            atomicAdd(&acc[4*2048  + bc], drow * dS0);
            atomicAdd(&acc[5*2048  + bc], drow * drow * dS0);
            unsigned long long pk = ((unsigned long long)ordf(M) << 32)
                                  | (unsigned)(16383 - (row * 128 + P));
            atomicMax(&apack[bc], pk);
        }
        // next-iter tile writes are fenced by B4 (combine reads scb, not tile;
        // next scb write happens only after next B3)
    }
}

__global__ __launch_bounds__(256) void k4_final(const double* __restrict__ acc,
                                                const unsigned long long* __restrict__ apack,
                                                const double* __restrict__ ga,
                                                float* __restrict__ out) {
    const int t = threadIdx.x;
    double dsum = 0, sfsum = 0, s0sum = 0;
    for (int bc = t; bc < NBC; bc += 256) {
        double sf  = acc[bc],          s0  = acc[2048 + bc];
        double sj  = acc[2*2048 + bc], sqj = acc[3*2048 + bc];
        double si  = acc[4*2048 + bc], sqi = acc[5*2048 + bc];
        int p = 16383 - (int)(apack[bc] & 0xFFFFFFFFull);
        double mi = (double)(p >> 7), mj = (double)(p & 127);
        dsum  += (mi*mi + mj*mj) * s0 + (sqi + sqj) - 2.0 * (mi*si + mj*sj);
        sfsum += sf; s0sum += s0;
    }
    __shared__ double rd[3][256];
    rd[0][t] = dsum; rd[1][t] = sfsum; rd[2][t] = s0sum;
    __syncthreads();
    for (int off = 128; off > 0; off >>= 1) {
        if (t < off) {
            rd[0][t] += rd[0][t + off];
            rd[1][t] += rd[1][t + off];
            rd[2][t] += rd[2][t + off];
        }
        __syncthreads();
    }
    if (t == 0) {
        const double n = 33554432.0;   // 32*64*128*128
        double mgr = rd[1][0] / n;
        out[0] = (float)(rd[0][0] / n);
        out[1] = (float)((ga[0] - 2.0 * mgr * ga[1] + mgr * mgr * rd[2][0]) / n);
    }
}

extern "C" void kernel_launch(void* const* d_in, const int* in_sizes, int n_in,
                              void* d_out, int out_size, void* d_ws, size_t ws_size,
                              hipStream_t stream) {
    const float* feat = (const float*)d_in[0];
    float* out = (float*)d_out;
    char* ws = (char*)d_ws;

    double* acc = (double*)ws;
    unsigned long long* apack = (unsigned long long*)(ws + 6*2048*8);
    double* ga = (double*)(ws + 6*2048*8 + 2048*8);

    hipMemsetAsync(ws, 0, WS_ZERO_BYTES, stream);
    f_fused<<<NBG, 256, 0, stream>>>(feat, acc, apack, ga);
    k4_final<<<1, 256, 0, stream>>>(acc, apack, ga, out);
}

// Round 12
// 76.730 us; speedup vs baseline: 2.9026x; 2.9026x over previous
//
#include <hip/hip_runtime.h>

#define HW    16384
#define WDIM  128
#define CDIM  64
#define BDIM  32
#define NSL   16                 // slices per image (1024 px each)
#define NBLK  (BDIM * NSL)       // 512 blocks
#define NBC   2048
#define SLOTSTRIDE 137           // padded c-stride in dwords (16*8 + 9, odd: ~2-way banks)

// acc layout: float[((c*32 + b)*16 + slice)*8]  {sf,s0,sj,sqj,si,sqi,hi,lo}
// ablk:       float[512][2]                      {a1,a2} per block

__device__ __forceinline__ unsigned ordf(float x) {
    unsigned u = __float_as_uint(x);
    return u ^ ((u >> 31) ? 0xFFFFFFFFu : 0x80000000u);  // monotone order-preserving
}

// one DPP prefix step: x += lane(i-N) within 16-lane row (0 outside)
template<int CTRL>
__device__ __forceinline__ float dpp_addstep(float x) {
    int m = __builtin_amdgcn_update_dpp(0, __float_as_int(x), CTRL, 0xf, 0xf, true);
    return x + __int_as_float(m);
}

// 16-lane prefix sum via DPP row_shr (VALU pipe, no DS, no barriers).
// After 4 stages lanes 15/31/47/63 hold their 16-lane totals.
__device__ __forceinline__ float red16(float x) {
    x = dpp_addstep<0x111>(x);   // row_shr:1
    x = dpp_addstep<0x112>(x);   // row_shr:2
    x = dpp_addstep<0x114>(x);   // row_shr:4
    x = dpp_addstep<0x118>(x);   // row_shr:8
    return x;
}

// one DPP lexicographic-max prefix step on (hi,lo)
template<int CTRL>
__device__ __forceinline__ void dpp_lexstep(unsigned& hi, unsigned& lo) {
    unsigned nh = (unsigned)__builtin_amdgcn_update_dpp(0, (int)hi, CTRL, 0xf, 0xf, true);
    unsigned nl = (unsigned)__builtin_amdgcn_update_dpp(0, (int)lo, CTRL, 0xf, 0xf, true);
    bool take = (nh > hi) || (nh == hi && nl > lo);
    hi = take ? nh : hi;
    lo = take ? nl : lo;
}

__device__ __forceinline__ void lexmax16(unsigned& hi, unsigned& lo) {
    dpp_lexstep<0x111>(hi, lo);
    dpp_lexstep<0x112>(hi, lo);
    dpp_lexstep<0x114>(hi, lo);
    dpp_lexstep<0x118>(hi, lo);
}

// Single pass, barrier-free hot loop. Block = (b, slice of 1024 px).
// Thread owns 4 consecutive px, loops c. Pixel-direction in registers;
// channel-direction reduced per-c across 16-lane rows via DPP, lane 15
// writes one 8-dword LDS slot. A/B ping-pong keeps 8-16 loads in flight.
__global__ __launch_bounds__(256, 2) void f_onepass(const float* __restrict__ feat,
                                                    float* __restrict__ acc,
                                                    float* __restrict__ ablk) {
    __shared__ float slots[CDIM * SLOTSTRIDE];   // ~35 KB
    __shared__ float ared[32];

    const int t   = threadIdx.x;
    const int blk = blockIdx.x;
    const int b   = blk >> 4, sl = blk & 15;
    const int px0 = sl * 1024 + t * 4;           // 4 px, same row (4 | 128)
    const float fi  = (float)(px0 >> 7);
    const float fi2 = fi * fi;
    const float fj0 = (float)(px0 & 127);
    const int  rowslot = t >> 4;                 // 16 rows of 16 lanes per block
    const bool tail    = ((t & 15) == 15);
    const float* src = feat + (size_t)b * (CDIM * HW) + px0;

    float m1[4], m2[4], s2[4];
    #pragma unroll
    for (int e = 0; e < 4; ++e) { m1[e] = -INFINITY; m2[e] = -INFINITY; s2[e] = 0.f; }

    float4 A[8], B[8];
    #pragma unroll
    for (int k = 0; k < 8; ++k) A[k] = *(const float4*)(src + (size_t)k * HW);
    #pragma unroll
    for (int k = 0; k < 8; ++k) B[k] = *(const float4*)(src + (size_t)(k + 8) * HW);
    __builtin_amdgcn_sched_barrier(0);

    auto process8 = [&](float4 (&buf)[8], int cbase) {
        #pragma unroll
        for (int k = 0; k < 8; ++k) {
            const int c = cbase + k;
            float x0 = buf[k].x, x1 = buf[k].y, x2 = buf[k].z, x3 = buf[k].w;
            // pixel-direction: top2 + S2 per owned pixel (m1>=m2 invariant)
            m2[0] = __builtin_amdgcn_fmed3f(x0, m1[0], m2[0]); m1[0] = fmaxf(m1[0], x0); s2[0] = fmaf(x0, x0, s2[0]);
            m2[1] = __builtin_amdgcn_fmed3f(x1, m1[1], m2[1]); m1[1] = fmaxf(m1[1], x1); s2[1] = fmaf(x1, x1, s2[1]);
            m2[2] = __builtin_amdgcn_fmed3f(x2, m1[2], m2[2]); m1[2] = fmaxf(m1[2], x2); s2[2] = fmaf(x2, x2, s2[2]);
            m2[3] = __builtin_amdgcn_fmed3f(x3, m1[3], m2[3]); m1[3] = fmaxf(m1[3], x3); s2[3] = fmaf(x3, x3, s2[3]);
            // channel-direction thread partials (4 px, shared row fi)
            float q0 = x0*x0, q1 = x1*x1, q2 = x2*x2, q3 = x3*x3;
            float sf = (x0 + x1) + (x2 + x3);
            float s0 = (q0 + q1) + (q2 + q3);
            float sj = fmaf(q3, fj0 + 3.f, fmaf(q2, fj0 + 2.f, fmaf(q1, fj0 + 1.f, q0 * fj0)));
            float sqj = fmaf(q3, (fj0+3.f)*(fj0+3.f), fmaf(q2, (fj0+2.f)*(fj0+2.f),
                        fmaf(q1, (fj0+1.f)*(fj0+1.f), q0 * (fj0*fj0))));
            float si = fi * s0, sqi = fi2 * s0;
            float bm = x0; int bj = 0;                 // ascending: first occurrence
            if (x1 > bm) { bm = x1; bj = 1; }
            if (x2 > bm) { bm = x2; bj = 2; }
            if (x3 > bm) { bm = x3; bj = 3; }
            unsigned hi = ordf(bm);
            unsigned lo = 16383u - (unsigned)(px0 + bj); // bigger = earlier
            // 16-lane DPP reductions
            sf = red16(sf); s0 = red16(s0); sj = red16(sj);
            sqj = red16(sqj); si = red16(si); sqi = red16(sqi);
            lexmax16(hi, lo);
            if (tail) {
                float* s = &slots[c * SLOTSTRIDE + rowslot * 8];
                s[0] = sf; s[1] = s0; s[2] = sj; s[3] = sqj;
                s[4] = si; s[5] = sqi;
                s[6] = __uint_as_float(hi); s[7] = __uint_as_float(lo);
            }
        }
    };

    for (int c0 = 0; c0 < 64; c0 += 16) {
        process8(A, c0);
        if (c0 < 48) {
            #pragma unroll
            for (int k = 0; k < 8; ++k) A[k] = *(const float4*)(src + (size_t)(c0 + 16 + k) * HW);
            __builtin_amdgcn_sched_barrier(0);
        }
        process8(B, c0 + 8);
        if (c0 < 48) {
            #pragma unroll
            for (int k = 0; k < 8; ++k) B[k] = *(const float4*)(src + (size_t)(c0 + 24 + k) * HW);
            __builtin_amdgcn_sched_barrier(0);
        }
    }

    // pixel-direction closed form per owned pixel, then 16-lane reduce
    float a1 = 0.f, a2 = 0.f;
    #pragma unroll
    for (int e = 0; e < 4; ++e) {
        float q = m1[e] * m1[e], r = s2[e] - q;
        a1 += q * r + m2[e] * m2[e] * q;
        a2 += m1[e] * r + m2[e] * q;
    }
    a1 = red16(a1); a2 = red16(a2);
    if (tail) { ared[rowslot * 2] = a1; ared[rowslot * 2 + 1] = a2; }
    __syncthreads();   // only barrier in the kernel

    if (t < 64) {      // combine 16 row-slots for channel c = t, write slice record
        const int c = t;
        float SF = 0, S0 = 0, SJ = 0, SQJ = 0, SI = 0, SQI = 0;
        unsigned HI = 0, LO = 0;
        #pragma unroll
        for (int rs = 0; rs < 16; ++rs) {
            const float* s = &slots[c * SLOTSTRIDE + rs * 8];
            SF += s[0]; S0 += s[1]; SJ += s[2]; SQJ += s[3];
            SI += s[4]; SQI += s[5];
            unsigned nh = __float_as_uint(s[6]), nl = __float_as_uint(s[7]);
            bool take = (nh > HI) || (nh == HI && nl > LO);
            HI = take ? nh : HI; LO = take ? nl : LO;
        }
        float* g = &acc[(((size_t)c * 32 + b) * 16 + sl) * 8];
        g[0] = SF; g[1] = S0; g[2] = SJ; g[3] = SQJ;
        g[4] = SI; g[5] = SQI;
        g[6] = __uint_as_float(HI); g[7] = __uint_as_float(LO);
    } else if (t == 255) {
        float A1 = 0, A2 = 0;
        #pragma unroll
        for (int rs = 0; rs < 16; ++rs) { A1 += ared[rs * 2]; A2 += ared[rs * 2 + 1]; }
        ablk[blk * 2] = A1; ablk[blk * 2 + 1] = A2;
    }
}

__global__ __launch_bounds__(256) void k4_final(const float* __restrict__ acc,
                                                const float* __restrict__ ablk,
                                                float* __restrict__ out) {
    const int t = threadIdx.x;
    double dsum = 0, sfsum = 0, s0sum = 0, a1 = 0, a2 = 0;
    for (int bc = t; bc < NBC; bc += 256) {       // bc = c*32 + b
        double SF = 0, S0 = 0, SJ = 0, SQJ = 0, SI = 0, SQI = 0;
        unsigned long long PK = 0;
        for (int s = 0; s < 16; ++s) {
            const float* g = &acc[((size_t)bc * 16 + s) * 8];
            SF += g[0]; S0 += g[1]; SJ += g[2]; SQJ += g[3];
            SI += g[4]; SQI += g[5];
            unsigned long long pk = ((unsigned long long)__float_as_uint(g[6]) << 32)
                                  | (unsigned long long)__float_as_uint(g[7]);
            PK = pk > PK ? pk : PK;
        }
        int p = 16383 - (int)(PK & 0xFFFFFFFFull);
        double mi = (double)(p >> 7), mj = (double)(p & 127);
        dsum  += (mi*mi + mj*mj) * S0 + (SQI + SQJ) - 2.0 * (mi*SI + mj*SJ);
        sfsum += SF; s0sum += S0;
    }
    for (int i = t; i < NBLK; i += 256) { a1 += ablk[i*2]; a2 += ablk[i*2 + 1]; }

    __shared__ double r[5][256];
    r[0][t] = dsum; r[1][t] = sfsum; r[2][t] = s0sum; r[3][t] = a1; r[4][t] = a2;
    __syncthreads();
    for (int off = 128; off > 0; off >>= 1) {
        if (t < off) {
            #pragma unroll
            for (int q = 0; q < 5; ++q) r[q][t] += r[q][t + off];
        }
        __syncthreads();
    }
    if (t == 0) {
        const double n = 33554432.0;   // 32*64*128*128
        double mgr = r[1][0] / n;
        out[0] = (float)(r[0][0] / n);
        out[1] = (float)((r[3][0] - 2.0 * mgr * r[4][0] + mgr * mgr * r[2][0]) / n);
    }
}

extern "C" void kernel_launch(void* const* d_in, const int* in_sizes, int n_in,
                              void* d_out, int out_size, void* d_ws, size_t ws_size,
                              hipStream_t stream) {
    const float* feat = (const float*)d_in[0];
    float* out = (float*)d_out;
    float* acc  = (float*)d_ws;                       // 1 MB
    float* ablk = (float*)d_ws + NBC * 16 * 8;        // 4 KB

    f_onepass<<<NBLK, 256, 0, stream>>>(feat, acc, ablk);
    k4_final<<<1, 256, 0, stream>>>(acc, ablk, out);
}